// Round 1
// baseline (1572.386 us; speedup 1.0000x reference)
//
#include <hip/hip_runtime.h>
#include <hip/hip_bf16.h>

#define ED 128
#define RR 8

typedef __attribute__((ext_vector_type(8))) short short8;   // 8 x bf16 (4 VGPRs)
typedef __attribute__((ext_vector_type(4))) float f32x4;    // MFMA accumulator

__device__ __forceinline__ unsigned short f2bf(float f){
  unsigned int u = __builtin_bit_cast(unsigned int, f);
  return (unsigned short)((u + 0x7fffu + ((u >> 16) & 1u)) >> 16);   // RNE
}
__device__ __forceinline__ float bf2f(unsigned int lo){
  return __builtin_bit_cast(float, lo << 16);
}

// ---- cast f32 -> bf16, 4 at a time ----
__global__ void cast_bf16_vec(const float4* __restrict__ in, ushort4* __restrict__ out, int n4){
  int stride = gridDim.x * blockDim.x;
  for (int i = blockIdx.x * blockDim.x + threadIdx.x; i < n4; i += stride){
    float4 v = in[i];
    ushort4 o;
    o.x = f2bf(v.x); o.y = f2bf(v.y); o.z = f2bf(v.z); o.w = f2bf(v.w);
    out[i] = o;
  }
}

// ---- per-(rel,dst) degree count ----
__global__ void deg_count(const int* __restrict__ rel, const int* __restrict__ dst,
                          float* __restrict__ deg, int E, int n){
  int stride = gridDim.x * blockDim.x;
  for (int i = blockIdx.x * blockDim.x + threadIdx.x; i < E; i += stride)
    atomicAdd(&deg[rel[i] * n + dst[i]], 1.0f);
}

// ---- z[s][r][j] = sum_k x[s][k] * W[r][j][k], bf16 in/out, f32 accum via MFMA ----
// grid: (ceil(n/128), R), block 256 (4 waves x 32 nodes each)
__launch_bounds__(256)
__global__ void rgcn_gemm(const unsigned short* __restrict__ xb,
                          const unsigned short* __restrict__ wb,
                          unsigned short* __restrict__ z, int n){
  const int r    = blockIdx.y;
  const int wave = threadIdx.x >> 6;
  const int lane = threadIdx.x & 63;
  const int ibase = blockIdx.x * 128 + wave * 32;
  const int frow = lane & 15;     // A row / B col within tile
  const int kb   = lane >> 4;     // k-block (8 contiguous k per lane)
  const unsigned short* wr = wb + (r << 14);

  // A fragments: 2 row-tiles x 4 k-steps (K=128)
  short8 a[2][4];
#pragma unroll
  for (int rt = 0; rt < 2; ++rt){
    int i = ibase + rt * 16 + frow;
    if (i >= n) i = n - 1;                       // clamp; store is masked
    const unsigned short* xp = xb + (size_t)i * ED + kb * 8;
#pragma unroll
    for (int kk = 0; kk < 4; ++kk)
      a[rt][kk] = *(const short8*)(xp + kk * 32);
  }

  f32x4 acc[2][8];
#pragma unroll
  for (int rt = 0; rt < 2; ++rt)
#pragma unroll
    for (int jt = 0; jt < 8; ++jt)
      acc[rt][jt] = (f32x4){0.f, 0.f, 0.f, 0.f};

#pragma unroll
  for (int jt = 0; jt < 8; ++jt){
    const unsigned short* wp = wr + (size_t)(jt * 16 + frow) * ED + kb * 8;
    short8 b[4];
#pragma unroll
    for (int kk = 0; kk < 4; ++kk)
      b[kk] = *(const short8*)(wp + kk * 32);    // B[k][j] = W[j][k], k contiguous
#pragma unroll
    for (int rt = 0; rt < 2; ++rt)
#pragma unroll
      for (int kk = 0; kk < 4; ++kk)
        acc[rt][jt] = __builtin_amdgcn_mfma_f32_16x16x32_bf16(a[rt][kk], b[kk], acc[rt][jt], 0, 0, 0);
  }

  // D layout: col = lane&15, row = (lane>>4)*4 + reg   [verified m89]
  const int drow = (lane >> 4) * 4;
  const int dcol = lane & 15;
#pragma unroll
  for (int rt = 0; rt < 2; ++rt)
#pragma unroll
    for (int jt = 0; jt < 8; ++jt)
#pragma unroll
      for (int reg = 0; reg < 4; ++reg){
        int i = ibase + rt * 16 + drow + reg;
        if (i < n)
          z[((size_t)i * RR + r) * ED + jt * 16 + dcol] = f2bf(acc[rt][jt][reg]);
      }
}

// ---- edge pass: one wave per edge; out[d] += z[s,r] / deg[r,d] ----
__launch_bounds__(256)
__global__ void edge_scatter(const unsigned short* __restrict__ z, const float* __restrict__ deg,
                             const int* __restrict__ rel, const int* __restrict__ src,
                             const int* __restrict__ dst, float* __restrict__ out, int E, int n){
  int gid  = blockIdx.x * blockDim.x + threadIdx.x;
  int lane = gid & 63;
  int wv   = gid >> 6;
  int nw   = (gridDim.x * blockDim.x) >> 6;
  for (int e = wv; e < E; e += nw){
    int r = rel[e], s = src[e], d = dst[e];
    float scale = 1.0f / deg[r * n + d];
    const unsigned int* zp = (const unsigned int*)(z + ((size_t)s * RR + r) * ED);
    unsigned int v = zp[lane];                  // 64 lanes x 4B = 256B coalesced
    float* op = out + (size_t)d * ED + lane * 2;
    atomicAdd(op,     bf2f(v & 0xffffu) * scale);
    atomicAdd(op + 1, bf2f(v >> 16)     * scale);
  }
}

__global__ void relu_vec(float4* __restrict__ out, int n4){
  int stride = gridDim.x * blockDim.x;
  for (int i = blockIdx.x * blockDim.x + threadIdx.x; i < n4; i += stride){
    float4 v = out[i];
    v.x = fmaxf(v.x, 0.f); v.y = fmaxf(v.y, 0.f);
    v.z = fmaxf(v.z, 0.f); v.w = fmaxf(v.w, 0.f);
    out[i] = v;
  }
}

extern "C" void kernel_launch(void* const* d_in, const int* in_sizes, int n_in,
                              void* d_out, int out_size, void* d_ws, size_t ws_size,
                              hipStream_t stream){
  const float* x  = (const float*)d_in[0];
  const float* w  = (const float*)d_in[1];
  const int* erel = (const int*)d_in[2];
  const int* esrc = (const int*)d_in[3];
  const int* edst = (const int*)d_in[4];
  float* out = (float*)d_out;

  const int n = in_sizes[0] / ED;          // 100000
  const int E = in_sizes[2];               // 1600000

  // workspace layout (all 16B-aligned offsets)
  char* ws = (char*)d_ws;
  size_t z_bytes  = (size_t)n * RR * ED * 2;        // 204.8 MB bf16
  size_t xb_bytes = (size_t)n * ED * 2;             // 25.6 MB bf16
  size_t wb_bytes = (size_t)RR * ED * ED * 2;       // 256 KB bf16
  size_t deg_bytes = (size_t)RR * n * 4;            // 3.2 MB f32
  if (ws_size < z_bytes + xb_bytes + wb_bytes + deg_bytes) return;

  unsigned short* z   = (unsigned short*)ws;
  unsigned short* xb  = (unsigned short*)(ws + z_bytes);
  unsigned short* wbp = (unsigned short*)(ws + z_bytes + xb_bytes);
  float*          deg = (float*)(ws + z_bytes + xb_bytes + wb_bytes);

  hipMemsetAsync(out, 0, (size_t)out_size * 4, stream);   // atomic accumulator: re-zero every call
  hipMemsetAsync(deg, 0, deg_bytes, stream);

  cast_bf16_vec<<<2048, 256, 0, stream>>>((const float4*)x, (ushort4*)xb, n * ED / 4);
  cast_bf16_vec<<<64,   256, 0, stream>>>((const float4*)w, (ushort4*)wbp, RR * ED * ED / 4);
  deg_count<<<1024, 256, 0, stream>>>(erel, edst, deg, E, n);
  rgcn_gemm<<<dim3((n + 127) / 128, RR), 256, 0, stream>>>(xb, wbp, z, n);
  edge_scatter<<<2048, 256, 0, stream>>>(z, deg, erel, esrc, edst, out, E, n);
  relu_vec<<<2048, 256, 0, stream>>>((float4*)out, (n * ED) / 4);
}

// Round 2
// 576.732 us; speedup vs baseline: 2.7264x; 2.7264x over previous
//
#include <hip/hip_runtime.h>
#include <hip/hip_bf16.h>

#define ED 128
#define RR 8
#define KTOT (RR * ED)   // 1024

typedef __attribute__((ext_vector_type(8))) short short8;   // 8 x bf16
typedef __attribute__((ext_vector_type(4))) float f32x4;    // MFMA accumulator

__device__ __forceinline__ unsigned short f2bf(float f){
  unsigned int u = __builtin_bit_cast(unsigned int, f);
  return (unsigned short)((u + 0x7fffu + ((u >> 16) & 1u)) >> 16);   // RNE
}
__device__ __forceinline__ float bf2f(unsigned int lo){
  return __builtin_bit_cast(float, lo << 16);
}

// ---- cast f32 -> bf16, 4 at a time ----
__global__ void cast_bf16_vec(const float4* __restrict__ in, ushort4* __restrict__ out, int n4){
  int stride = gridDim.x * blockDim.x;
  for (int i = blockIdx.x * blockDim.x + threadIdx.x; i < n4; i += stride){
    float4 v = in[i];
    ushort4 o;
    o.x = f2bf(v.x); o.y = f2bf(v.y); o.z = f2bf(v.z); o.w = f2bf(v.w);
    out[i] = o;
  }
}

// ---- w2t[j][r*128+kk] = W[r][j][kk]  (B^T layout for the MFMA fragment) ----
__global__ void build_w2t(const float* __restrict__ w, unsigned short* __restrict__ w2t){
  int idx = blockIdx.x * blockDim.x + threadIdx.x;     // over R*ED*ED = 131072
  int kk = idx & 127;
  int j  = (idx >> 7) & 127;
  int r  = idx >> 14;
  w2t[j * KTOT + r * ED + kk] = f2bf(w[idx]);
}

// ---- histogram of dst ----
__global__ void hist_dst(const int* __restrict__ dst, int* __restrict__ rowcnt, int E){
  int stride = gridDim.x * blockDim.x;
  for (int i = blockIdx.x * blockDim.x + threadIdx.x; i < E; i += stride)
    atomicAdd(&rowcnt[dst[i]], 1);
}

// ---- scan step 1: per-block (1024) sums ----
__launch_bounds__(1024)
__global__ void scan_block_sum(const int* __restrict__ rowcnt, int* __restrict__ bsum, int n){
  __shared__ int lds[16];
  int t = threadIdx.x;
  int idx = blockIdx.x * 1024 + t;
  int v = (idx < n) ? rowcnt[idx] : 0;
#pragma unroll
  for (int o = 32; o > 0; o >>= 1) v += __shfl_down(v, o);
  if ((t & 63) == 0) lds[t >> 6] = v;
  __syncthreads();
  if (t == 0){
    int s = 0;
#pragma unroll
    for (int w = 0; w < 16; ++w) s += lds[w];
    bsum[blockIdx.x] = s;
  }
}

// ---- scan step 2: serial exclusive scan of block sums (tiny) ----
__global__ void scan_bsum(const int* __restrict__ bsum, int* __restrict__ bscan,
                          int nb, int* __restrict__ total_out){
  if (threadIdx.x == 0 && blockIdx.x == 0){
    int acc = 0;
    for (int b = 0; b < nb; ++b){ bscan[b] = acc; acc += bsum[b]; }
    *total_out = acc;             // row_ptr[n]
  }
}

// ---- scan step 3: block-level exclusive scan + block offset ----
__launch_bounds__(1024)
__global__ void scan_final(const int* __restrict__ rowcnt, const int* __restrict__ bscan,
                           int* __restrict__ row_ptr, int n){
  __shared__ int lds[1024];
  int t = threadIdx.x;
  int idx = blockIdx.x * 1024 + t;
  int v = (idx < n) ? rowcnt[idx] : 0;
  lds[t] = v;
  __syncthreads();
#pragma unroll
  for (int o = 1; o < 1024; o <<= 1){
    int u = (t >= o) ? lds[t - o] : 0;
    __syncthreads();
    lds[t] += u;
    __syncthreads();
  }
  if (idx < n) row_ptr[idx] = lds[t] - v + bscan[blockIdx.x];   // exclusive
}

// ---- cursor = row_ptr (copy) ----
__global__ void copy_int(const int* __restrict__ a, int* __restrict__ b, int n){
  int stride = gridDim.x * blockDim.x;
  for (int i = blockIdx.x * blockDim.x + threadIdx.x; i < n; i += stride) b[i] = a[i];
}

// ---- bucket-scatter edges into CSR payload: payload[pos] = src*8 + rel ----
__global__ void scatter_build(const int* __restrict__ rel, const int* __restrict__ src,
                              const int* __restrict__ dst, int* __restrict__ cursor,
                              int* __restrict__ payload, int E){
  int stride = gridDim.x * blockDim.x;
  for (int i = blockIdx.x * blockDim.x + threadIdx.x; i < E; i += stride){
    int d = dst[i];
    int pos = atomicAdd(&cursor[d], 1);
    payload[pos] = (src[i] << 3) | rel[i];
  }
}

// ---- one wave per node: h2[d][r*128+k] = mean of xb[src][k] over edges (d, r) ----
__launch_bounds__(256)
__global__ void row_agg(const unsigned short* __restrict__ xb, const int* __restrict__ row_ptr,
                        const int* __restrict__ payload, unsigned short* __restrict__ h2, int n){
  int wv   = (blockIdx.x * 256 + threadIdx.x) >> 6;   // node id
  int lane = threadIdx.x & 63;
  if (wv >= n) return;
  int beg = row_ptr[wv], end = row_ptr[wv + 1];

  float2 acc[RR];
  int    cnt[RR];
#pragma unroll
  for (int r = 0; r < RR; ++r){ acc[r] = make_float2(0.f, 0.f); cnt[r] = 0; }

  for (int e = beg; e < end; ++e){
    int p = payload[e];                                // wave-uniform broadcast load
    int s = p >> 3, r = p & 7;
    unsigned int v = ((const unsigned int*)(xb + (size_t)s * ED))[lane];  // 256B coalesced
    float lo = bf2f(v & 0xffffu), hi = bf2f(v >> 16);
    switch (r){                                        // r wave-uniform -> scalar branch
#define AGG_CASE(R) case R: acc[R].x += lo; acc[R].y += hi; cnt[R]++; break;
      AGG_CASE(0) AGG_CASE(1) AGG_CASE(2) AGG_CASE(3)
      AGG_CASE(4) AGG_CASE(5) AGG_CASE(6) AGG_CASE(7)
#undef AGG_CASE
    }
  }

  unsigned short* hp = h2 + (size_t)wv * KTOT + lane * 2;
#pragma unroll
  for (int r = 0; r < RR; ++r){
    float sc = cnt[r] ? 1.f / (float)cnt[r] : 0.f;
    unsigned int o = ((unsigned int)f2bf(acc[r].y * sc) << 16) | f2bf(acc[r].x * sc);
    *(unsigned int*)(hp + r * ED) = o;
  }
}

// ---- out[d][j] = relu( sum_k h2[d][k] * w2t[j][k] ), K = 1024, MFMA 16x16x32 ----
__launch_bounds__(256)
__global__ void gemm_out(const unsigned short* __restrict__ h2,
                         const unsigned short* __restrict__ w2t,
                         float* __restrict__ out, int n){
  const int wave = threadIdx.x >> 6;
  const int lane = threadIdx.x & 63;
  const int ibase = blockIdx.x * 128 + wave * 32;
  const int frow = lane & 15;
  const int kb   = lane >> 4;

  f32x4 acc[2][8];
#pragma unroll
  for (int rt = 0; rt < 2; ++rt)
#pragma unroll
    for (int jt = 0; jt < 8; ++jt)
      acc[rt][jt] = (f32x4){0.f, 0.f, 0.f, 0.f};

  int i0 = ibase + frow;      if (i0 >= n) i0 = n - 1;
  int i1 = ibase + 16 + frow; if (i1 >= n) i1 = n - 1;
  const unsigned short* ap0 = h2 + (size_t)i0 * KTOT + kb * 8;
  const unsigned short* ap1 = h2 + (size_t)i1 * KTOT + kb * 8;

  for (int ks = 0; ks < KTOT / 32; ++ks){
    short8 a0 = *(const short8*)(ap0 + ks * 32);
    short8 a1 = *(const short8*)(ap1 + ks * 32);
#pragma unroll
    for (int jt = 0; jt < 8; ++jt){
      short8 b = *(const short8*)(w2t + (size_t)(jt * 16 + frow) * KTOT + ks * 32 + kb * 8);
      acc[0][jt] = __builtin_amdgcn_mfma_f32_16x16x32_bf16(a0, b, acc[0][jt], 0, 0, 0);
      acc[1][jt] = __builtin_amdgcn_mfma_f32_16x16x32_bf16(a1, b, acc[1][jt], 0, 0, 0);
    }
  }

  // D layout: col = lane&15, row = (lane>>4)*4 + reg
  const int drow = (lane >> 4) * 4;
  const int dcol = lane & 15;
#pragma unroll
  for (int rt = 0; rt < 2; ++rt)
#pragma unroll
    for (int jt = 0; jt < 8; ++jt)
#pragma unroll
      for (int reg = 0; reg < 4; ++reg){
        int i = ibase + rt * 16 + drow + reg;
        if (i < n)
          out[(size_t)i * ED + jt * 16 + dcol] = fmaxf(acc[rt][jt][reg], 0.f);
      }
}

extern "C" void kernel_launch(void* const* d_in, const int* in_sizes, int n_in,
                              void* d_out, int out_size, void* d_ws, size_t ws_size,
                              hipStream_t stream){
  const float* x  = (const float*)d_in[0];
  const float* w  = (const float*)d_in[1];
  const int* erel = (const int*)d_in[2];
  const int* esrc = (const int*)d_in[3];
  const int* edst = (const int*)d_in[4];
  float* out = (float*)d_out;

  const int n = in_sizes[0] / ED;          // 100000
  const int E = in_sizes[2];               // 1600000
  const int NB = (n + 1023) / 1024;        // scan blocks (98)

  // ---- workspace layout (256B-aligned segments) ----
  char* ws = (char*)d_ws;
  size_t off = 0;
  auto alloc = [&](size_t bytes) -> char* {
    char* p = ws + off;
    off += (bytes + 255) & ~(size_t)255;
    return p;
  };
  unsigned short* h2      = (unsigned short*)alloc((size_t)n * KTOT * 2);   // 204.8 MB
  unsigned short* xb      = (unsigned short*)alloc((size_t)n * ED * 2);     // 25.6 MB
  unsigned short* w2t     = (unsigned short*)alloc((size_t)RR * ED * ED * 2);
  int*            payload = (int*)alloc((size_t)E * 4);                     // 6.4 MB
  int*            row_ptr = (int*)alloc((size_t)(n + 1) * 4);
  int*            rowcnt  = (int*)alloc((size_t)n * 4);
  int*            cursor  = (int*)alloc((size_t)n * 4);
  int*            bsum    = (int*)alloc((size_t)NB * 4);
  int*            bscan   = (int*)alloc((size_t)NB * 4);
  if (off > ws_size) return;

  hipMemsetAsync(rowcnt, 0, (size_t)n * 4, stream);

  cast_bf16_vec<<<2048, 256, 0, stream>>>((const float4*)x, (ushort4*)xb, n * ED / 4);
  build_w2t   <<<(RR * ED * ED) / 256, 256, 0, stream>>>(w, w2t);
  hist_dst    <<<1024, 256, 0, stream>>>(edst, rowcnt, E);
  scan_block_sum<<<NB, 1024, 0, stream>>>(rowcnt, bsum, n);
  scan_bsum   <<<1, 64, 0, stream>>>(bsum, bscan, NB, row_ptr + n);
  scan_final  <<<NB, 1024, 0, stream>>>(rowcnt, bscan, row_ptr, n);
  copy_int    <<<256, 256, 0, stream>>>(row_ptr, cursor, n);
  scatter_build<<<1024, 256, 0, stream>>>(erel, esrc, edst, cursor, payload, E);
  row_agg     <<<(n + 3) / 4, 256, 0, stream>>>(xb, row_ptr, payload, h2, n);
  gemm_out    <<<(n + 127) / 128, 256, 0, stream>>>(h2, w2t, out, n);
}